// Round 13
// baseline (475.248 us; speedup 1.0000x reference)
//
#include <hip/hip_runtime.h>
#include <hip/hip_bf16.h>
#include <stdint.h>

#define NB 4
#define BS 4096
#define BH 512

typedef __attribute__((ext_vector_type(8))) short bf16x8;
typedef __attribute__((ext_vector_type(4))) float f32x4;

#define VMC(n) asm volatile("s_waitcnt vmcnt(" #n ")" ::: "memory")

static __device__ __forceinline__ ushort f2bf(float x) {
    union { float f; uint32_t u; } c; c.f = x;
    uint32_t r = c.u + 0x7FFFu + ((c.u >> 16) & 1u);
    return (ushort)(r >> 16);
}
static __device__ __forceinline__ float bf2f(ushort u) {
    union { uint32_t u; float f; } c; c.u = (uint32_t)u << 16;
    return c.f;
}

// async global -> LDS, 16B per lane. dest = wave-uniform base + lane*16.
static __device__ __forceinline__ void gl16(const void* gptr, void* lptr) {
    __builtin_amdgcn_global_load_lds(
        (const __attribute__((address_space(1))) void*)gptr,
        (__attribute__((address_space(3))) void*)lptr, 16, 0, 0);
}

// ---------------------------------------------------------------------------
// Fused projection GEMMs: z = 0/1/2 -> Q/K/V.  Y = X W^T + b, bf16 out.
// ---------------------------------------------------------------------------
__global__ __launch_bounds__(256) void proj_kernel(
    const float* __restrict__ Xq, const float* __restrict__ Xk, const float* __restrict__ Xv,
    const float* __restrict__ Wq, const float* __restrict__ bq,
    const float* __restrict__ Wk, const float* __restrict__ bk,
    const float* __restrict__ Wv, const float* __restrict__ bv,
    ushort* __restrict__ qb, ushort* __restrict__ kb, ushort* __restrict__ vT)
{
    const int z = blockIdx.z;
    const float* X    = (z == 0) ? Xq : (z == 1) ? Xk : Xv;
    const float* W    = (z == 0) ? Wq : (z == 1) ? Wk : Wv;
    const float* bias = (z == 0) ? bq : (z == 1) ? bk : bv;
    ushort* out       = (z == 0) ? qb : (z == 1) ? kb : vT;
    const bool TR = (z == 2);

    __shared__ ushort As[128 * 32];
    __shared__ ushort Bs[128 * 32];
    const int tid  = threadIdx.x;
    const int lane = tid & 63;
    const int wave = tid >> 6;
    const int wr = wave >> 1, wc = wave & 1;
    const int bi = blockIdx.y, bj = blockIdx.x;

    f32x4 acc[4][4];
    #pragma unroll
    for (int m = 0; m < 4; m++)
        #pragma unroll
        for (int n = 0; n < 4; n++) acc[m][n] = (f32x4)0.0f;

    const int r  = tid >> 1;
    const int kg = (tid & 1) * 16;
    const int kq = (lane >> 4) * 8;
    const int fr = lane & 15;

    for (int kt = 0; kt < 512; kt += 32) {
        {
            const float* src = X + (size_t)(bi * 128 + r) * 512 + kt + kg;
            ushort tmp[16];
            #pragma unroll
            for (int j = 0; j < 4; j++) {
                float4 v = *reinterpret_cast<const float4*>(src + j * 4);
                tmp[j*4+0] = f2bf(v.x); tmp[j*4+1] = f2bf(v.y);
                tmp[j*4+2] = f2bf(v.z); tmp[j*4+3] = f2bf(v.w);
            }
            ushort* dst = &As[r * 32 + kg];
            *reinterpret_cast<uint4*>(dst)     = *reinterpret_cast<const uint4*>(tmp);
            *reinterpret_cast<uint4*>(dst + 8) = *reinterpret_cast<const uint4*>(tmp + 8);
        }
        {
            const float* src = W + (size_t)(bj * 128 + r) * 512 + kt + kg;
            ushort tmp[16];
            #pragma unroll
            for (int j = 0; j < 4; j++) {
                float4 v = *reinterpret_cast<const float4*>(src + j * 4);
                tmp[j*4+0] = f2bf(v.x); tmp[j*4+1] = f2bf(v.y);
                tmp[j*4+2] = f2bf(v.z); tmp[j*4+3] = f2bf(v.w);
            }
            ushort* dst = &Bs[r * 32 + kg];
            *reinterpret_cast<uint4*>(dst)     = *reinterpret_cast<const uint4*>(tmp);
            *reinterpret_cast<uint4*>(dst + 8) = *reinterpret_cast<const uint4*>(tmp + 8);
        }
        __syncthreads();

        bf16x8 af[4], bf[4];
        #pragma unroll
        for (int m = 0; m < 4; m++)
            af[m] = *reinterpret_cast<const bf16x8*>(&As[(wr*64 + m*16 + fr) * 32 + kq]);
        #pragma unroll
        for (int n = 0; n < 4; n++)
            bf[n] = *reinterpret_cast<const bf16x8*>(&Bs[(wc*64 + n*16 + fr) * 32 + kq]);
        #pragma unroll
        for (int m = 0; m < 4; m++)
            #pragma unroll
            for (int n = 0; n < 4; n++)
                acc[m][n] = __builtin_amdgcn_mfma_f32_16x16x32_bf16(af[m], bf[n], acc[m][n], 0, 0, 0);
        __syncthreads();
    }

    const int fq = lane >> 4;
    #pragma unroll
    for (int n = 0; n < 4; n++) {
        const int col = bj * 128 + wc * 64 + n * 16 + fr;
        const float bv2 = bias[col];
        #pragma unroll
        for (int m = 0; m < 4; m++) {
            const int row0 = bi * 128 + wr * 64 + m * 16 + fq * 4;
            if (TR) {
                const int b = row0 >> 12;
                const int s = row0 & 4095;
                ushort4 pk;
                pk.x = f2bf(acc[m][n][0] + bv2);
                pk.y = f2bf(acc[m][n][1] + bv2);
                pk.z = f2bf(acc[m][n][2] + bv2);
                pk.w = f2bf(acc[m][n][3] + bv2);
                *reinterpret_cast<ushort4*>(&out[((size_t)b * 512 + col) * 4096 + s]) = pk;
            } else {
                #pragma unroll
                for (int j = 0; j < 4; j++)
                    out[(size_t)(row0 + j) * 512 + col] = f2bf(acc[m][n][j] + bv2);
            }
        }
    }
}

// ---------------------------------------------------------------------------
// QK^T 128x128 (R7 proven loop). Epilogue: e = exp(s*scale) scattered into
// the reused 32KB LDS tile, then COALESCED copy-out (1KB/inst). Partial row
// sums -> stats. Upper tiles: fp32 zeros to attn. Diag masked cells: E=0.
// ---------------------------------------------------------------------------
__global__ __launch_bounds__(256) void qk_kernel(const ushort* __restrict__ qb,
                                                 const ushort* __restrict__ kb,
                                                 float* __restrict__ attn,
                                                 ushort* __restrict__ Ews,
                                                 float* __restrict__ stats)
{
    // XCD-aware bijective swizzle: nwg = 4096
    const int flat = blockIdx.x + (blockIdx.y << 5) + (blockIdx.z << 10);
    const int s    = (flat & 7) * 512 + (flat >> 3);
    const int bj = s & 31, bi = (s >> 5) & 31, b = s >> 10;

    float* aout = attn + (size_t)b * BS * BS;
    const int tid = threadIdx.x;

    if (bj > bi) {  // fully masked tile -> fp32 zeros (final output value)
        const int r  = tid >> 1;
        const int cg = (tid & 1) * 64;
        float4 z = make_float4(0.f, 0.f, 0.f, 0.f);
        float* dst = aout + (size_t)(bi * 128 + r) * BS + bj * 128 + cg;
        #pragma unroll
        for (int j = 0; j < 16; j++) reinterpret_cast<float4*>(dst)[j] = z;
        return;
    }

    __shared__ ushort SH[4 * 128 * 32];   // A0|A1|B0|B1; epilogue: 128x128 E tile
    __shared__ float red[128][2];
    ushort* A0 = SH;
    ushort* A1 = SH + 4096;
    ushort* B0 = SH + 8192;
    ushort* B1 = SH + 12288;

    const int lane = tid & 63;
    const int wave = tid >> 6;
    const int wr = wave >> 1, wc = wave & 1;

    f32x4 acc[4][4];
    #pragma unroll
    for (int m = 0; m < 4; m++)
        #pragma unroll
        for (int n = 0; n < 4; n++) acc[m][n] = (f32x4)0.0f;

    const ushort* Qb = qb + (size_t)(b * BS + bi * 128) * 512;
    const ushort* Kb = kb + (size_t)(b * BS + bj * 128) * 512;

    const int c0 = wave * 2, c1 = wave * 2 + 1;
    const int glr = lane >> 2;
    const int gsw = ((lane & 3) ^ (glr & 3)) * 8;   // inverse-swizzled granule
    const ushort* ga0 = Qb + (size_t)(c0 * 16 + glr) * 512 + gsw;
    const ushort* ga1 = Qb + (size_t)(c1 * 16 + glr) * 512 + gsw;
    const ushort* gb0 = Kb + (size_t)(c0 * 16 + glr) * 512 + gsw;
    const ushort* gb1 = Kb + (size_t)(c1 * 16 + glr) * 512 + gsw;

    const int fr = lane & 15;
    const int fq = lane >> 4;
    const int kqs = (fq ^ (fr & 3)) * 8;   // swizzled read slot

    auto domfma = [&](const ushort* Ab, const ushort* Bb) {
        bf16x8 af[4], bf[4];
        #pragma unroll
        for (int m = 0; m < 4; m++)
            af[m] = *reinterpret_cast<const bf16x8*>(&Ab[(wr*64 + m*16 + fr) * 32 + kqs]);
        #pragma unroll
        for (int n = 0; n < 4; n++)
            bf[n] = *reinterpret_cast<const bf16x8*>(&Bb[(wc*64 + n*16 + fr) * 32 + kqs]);
        __builtin_amdgcn_s_setprio(1);
        #pragma unroll
        for (int m = 0; m < 4; m++)
            #pragma unroll
            for (int n = 0; n < 4; n++)
                acc[m][n] = __builtin_amdgcn_mfma_f32_16x16x32_bf16(af[m], bf[n], acc[m][n], 0, 0, 0);
        __builtin_amdgcn_s_setprio(0);
    };

    // prologue: stage tile 0 into buffers 0
    gl16(ga0, A0 + c0 * 512); gl16(ga1, A0 + c1 * 512);
    gl16(gb0, B0 + c0 * 512); gl16(gb1, B0 + c1 * 512);
    __syncthreads();

    for (int kt = 0; kt < 512; kt += 64) {
        gl16(ga0 + kt + 32, A1 + c0 * 512); gl16(ga1 + kt + 32, A1 + c1 * 512);
        gl16(gb0 + kt + 32, B1 + c0 * 512); gl16(gb1 + kt + 32, B1 + c1 * 512);
        domfma(A0, B0);
        __syncthreads();
        if (kt + 64 < 512) {
            gl16(ga0 + kt + 64, A0 + c0 * 512); gl16(ga1 + kt + 64, A0 + c1 * 512);
            gl16(gb0 + kt + 64, B0 + c0 * 512); gl16(gb1 + kt + 64, B0 + c1 * 512);
        }
        domfma(A1, B1);
        __syncthreads();
    }

    // ---- epilogue: e = exp(s*scale); scatter to LDS; coalesced copy-out ----
    const float scaling = 0.044194173824159216f;  // 1/sqrt(512)
    const bool diag = (bi == bj);

    #pragma unroll
    for (int m = 0; m < 4; m++) {
        #pragma unroll
        for (int j = 0; j < 4; j++) {
            const int r_loc = wr * 64 + m * 16 + fq * 4 + j;
            const int grow  = bi * 128 + r_loc;
            float sum = 0.0f;
            #pragma unroll
            for (int n = 0; n < 4; n++) {
                const int c_loc = wc * 64 + n * 16 + fr;
                const bool masked = diag && (bj * 128 + c_loc > grow);
                float e = masked ? 0.0f : __expf(acc[m][n][j] * scaling);
                SH[r_loc * 128 + c_loc] = f2bf(e);
                sum += e;
            }
            #pragma unroll
            for (int o = 1; o < 16; o <<= 1) sum += __shfl_xor(sum, o);
            if (fr == 0) red[r_loc][wc] = sum;
        }
    }
    __syncthreads();

    ushort* Eb = Ews + ((size_t)b << 24);
    const uint4* Esrc = reinterpret_cast<const uint4*>(SH);
    #pragma unroll
    for (int i = 0; i < 8; i++) {
        uint4 v = Esrc[i * 256 + tid];
        const int row  = i * 16 + (tid >> 4);
        const int col8 = (tid & 15) * 8;
        *reinterpret_cast<uint4*>(&Eb[(size_t)(bi * 128 + row) * BS + bj * 128 + col8]) = v;
    }
    if (tid < 128)
        stats[(size_t)(b * 32 + bj) * 4096 + bi * 128 + tid] = red[tid][0] + red[tid][1];
}

// ---------------------------------------------------------------------------
// Merge per-tile sums into per-row 1/sum AND zero ctx. Grid: 512 x 256.
// ---------------------------------------------------------------------------
__global__ __launch_bounds__(256) void reduce_kernel(const float* __restrict__ stats,
                                                     float* __restrict__ rowstat,
                                                     float4* __restrict__ ctx4)
{
    const int g = blockIdx.x * 256 + threadIdx.x;   // 0..131071
    const float4 z = make_float4(0.f, 0.f, 0.f, 0.f);
    #pragma unroll
    for (int i = 0; i < 16; i++)
        ctx4[(size_t)i * 131072 + g] = z;

    if (g < 16384) {
        const int b = g >> 12, i = g & 4095;
        const int nt = (i >> 7) + 1;
        float S = 0.0f;
        for (int t = 0; t < nt; t++)
            S += stats[(size_t)(b * 32 + t) * 4096 + i];
        rowstat[g] = 1.0f / S;
    }
}

// ---------------------------------------------------------------------------
// PV + attn-write. 64-thread wave-blocks, NO barriers, 8 KB LDS ->
// ~20 blocks/CU (2.5x R12 occupancy). Block = (batch, 32-row band,
// 1024-col k-chunk, 64-col H slice); 10240 blocks.
// V sub-tile (64h x 32k = 4KB) double-buffered via gl16, counted vmcnt;
// E read DIRECT global->register, prefetched one tile ahead (compiler-
// tracked). Slice 0 stores normalized fp32 attn. ctx via fp32 atomics.
// ---------------------------------------------------------------------------
__global__ __launch_bounds__(64) void pv_kernel(float* __restrict__ attn,
                                                const ushort* __restrict__ vT,
                                                const ushort* __restrict__ Ews,
                                                const float* __restrict__ rowstat,
                                                float* __restrict__ ctx)
{
    const int x = blockIdx.x;
    const int b = x & 3;
    const int r2 = x >> 2;
    const int slice = r2 & 7;                     // 64-col H slice
    const int f = r2 >> 3;                        // 0..319
    int w = 3;
    if (f < 32)       w = 0;
    else if (f < 96)  w = 1;
    else if (f < 192) w = 2;
    const int start = 16 * w * (w + 1);
    const int local = f - start;
    const int bi32  = (w << 5) + local / (w + 1);
    const int ks    = local % (w + 1);

    const int nt_cov = ((bi32 >> 2) + 1) << 2;    // cover to 128-tile boundary
    const int t0 = ks * 32;
    const int t1 = min(nt_cov, t0 + 32);

    __shared__ ushort V0[64 * 32], V1[64 * 32];   // 4 KB each

    const int lane = threadIdx.x;
    const int fr = lane & 15;
    const int fq = lane >> 4;
    const int kqs = (fq ^ (fr & 3)) * 8;

    f32x4 acc[2][4];
    #pragma unroll
    for (int m = 0; m < 2; m++)
        #pragma unroll
        for (int n = 0; n < 4; n++) acc[m][n] = (f32x4)0.0f;

    const int grow0 = bi32 * 32;
    const int col0  = slice * 64;
    const float rinv0 = rowstat[b * 4096 + grow0 + fr];
    const float rinv1 = rowstat[b * 4096 + grow0 + 16 + fr];

    const int glr = lane >> 2;
    const int gsw = ((lane & 3) ^ (glr & 3)) * 8;

    const ushort* Vb = vT + (size_t)b * 512 * BS;
    const ushort* gV[4];
    #pragma unroll
    for (int q = 0; q < 4; q++)
        gV[q] = Vb + (size_t)(col0 + q * 16 + glr) * BS + gsw;

    const ushort* Ebase = Ews + ((size_t)b << 24);
    const ushort* gE0 = Ebase + (size_t)(grow0 + fr) * BS + fq * 8;
    const ushort* gE1 = Ebase + (size_t)(grow0 + 16 + fr) * BS + fq * 8;

    float* AttnB = attn + (size_t)b * BS * BS;
    float* ast0 = AttnB + (size_t)(grow0 + fr) * BS + fq * 8;
    float* ast1 = AttnB + (size_t)(grow0 + 16 + fr) * BS + fq * 8;
    const bool do_store = (slice == 0);

    auto stageV = [&](int t, int buf) {
        const int k0 = t * 32;
        ushort* Vl = buf ? V1 : V0;
        #pragma unroll
        for (int q = 0; q < 4; q++) gl16(gV[q] + k0, &Vl[q * 512]);
    };

    // prologue: V(t0) staged, E(t0) in regs
    stageV(t0, 0);
    bf16x8 e0c = *reinterpret_cast<const bf16x8*>(gE0 + t0 * 32);
    bf16x8 e1c = *reinterpret_cast<const bf16x8*>(gE1 + t0 * 32);

    int cur = 0;
    for (int t = t0; t < t1; ++t) {
        const bool has = (t + 1 < t1);
        bf16x8 e0n, e1n;
        if (has) {
            stageV(t + 1, cur ^ 1);
            e0n = *reinterpret_cast<const bf16x8*>(gE0 + (t + 1) * 32);
            e1n = *reinterpret_cast<const bf16x8*>(gE1 + (t + 1) * 32);
        }
        // counted wait for V(t)+E(t) retired (in-order vmem retirement):
        // outstanding allowed = (this iter's 6: 4 gl16 + 2 E-loads) +
        // (prev-iter attn stores: 4, slice0 only, t>t0)
        if (has) {
            if (do_store && t > t0) { VMC(10); } else { VMC(6); }
        } else {
            if (do_store && t > t0) { VMC(4); } else { VMC(0); }
        }
        __builtin_amdgcn_sched_barrier(0);

        const ushort* Vl = cur ? V1 : V0;

        float p0[8], p1[8];
        #pragma unroll
        for (int j = 0; j < 8; j++) {
            p0[j] = bf2f((ushort)e0c[j]) * rinv0;
            p1[j] = bf2f((ushort)e1c[j]) * rinv1;
        }

        if (do_store) {   // normalized fp32 attn, coalesced 32B segments
            float* d0 = ast0 + (size_t)t * 32;
            float* d1 = ast1 + (size_t)t * 32;
            *reinterpret_cast<float4*>(d0)     = make_float4(p0[0], p0[1], p0[2], p0[3]);
            *reinterpret_cast<float4*>(d0 + 4) = make_float4(p0[4], p0[5], p0[6], p0[7]);
            *reinterpret_cast<float4*>(d1)     = make_float4(p1[0], p1[1], p1[2], p1[3]);
            *reinterpret_cast<float4*>(d1 + 4) = make_float4(p1[4], p1[5], p1[6], p1[7]);
        }

        bf16x8 a0, a1;
        #pragma unroll
        for (int j = 0; j < 8; j++) {
            a0[j] = (short)f2bf(p0[j]);
            a1[j] = (short)f2bf(p1[j]);
        }
        bf16x8 bv[4];
        #pragma unroll
        for (int n = 0; n < 4; n++)
            bv[n] = *reinterpret_cast<const bf16x8*>(&Vl[(n * 16 + fr) * 32 + kqs]);

        __builtin_amdgcn_s_setprio(1);
        #pragma unroll
        for (int n = 0; n < 4; n++) {
            acc[0][n] = __builtin_amdgcn_mfma_f32_16x16x32_bf16(a0, bv[n], acc[0][n], 0, 0, 0);
            acc[1][n] = __builtin_amdgcn_mfma_f32_16x16x32_bf16(a1, bv[n], acc[1][n], 0, 0, 0);
        }
        __builtin_amdgcn_s_setprio(0);

        e0c = e0n; e1c = e1n;
        cur ^= 1;
    }

    float* Crow = ctx + (size_t)b * BS * 512;
    const bool single = (w == 0);
    #pragma unroll
    for (int n = 0; n < 4; n++) {
        const int col = col0 + n * 16 + fr;
        #pragma unroll
        for (int m = 0; m < 2; m++) {
            const int row0 = grow0 + m * 16 + fq * 4;
            #pragma unroll
            for (int j = 0; j < 4; j++) {
                float* dst = &Crow[(size_t)(row0 + j) * 512 + col];
                if (single) *dst = acc[m][n][j];
                else        unsafeAtomicAdd(dst, acc[m][n][j]);
            }
        }
    }
}

extern "C" void kernel_launch(void* const* d_in, const int* in_sizes, int n_in,
                              void* d_out, int out_size, void* d_ws, size_t ws_size,
                              hipStream_t stream)
{
    const float* queries = (const float*)d_in[0];
    const float* keys    = (const float*)d_in[1];
    const float* values  = (const float*)d_in[2];
    const float* Wq = (const float*)d_in[3];
    const float* bq = (const float*)d_in[4];
    const float* Wk = (const float*)d_in[5];
    const float* bk = (const float*)d_in[6];
    const float* Wv = (const float*)d_in[7];
    const float* bv = (const float*)d_in[8];

    float* ctx  = (float*)d_out;                         // [B,S,H]
    float* attn = (float*)d_out + (size_t)NB * BS * BH;  // [B,S,S]

    ushort* qb = (ushort*)d_ws;                          // bf16 [B*S, H]
    ushort* kb = qb + (size_t)NB * BS * BH;
    ushort* vT = kb + (size_t)NB * BS * BH;              // bf16 [B][H][S]
    ushort* Ews = vT + (size_t)NB * BH * BS;             // bf16 [B][S][S]
    float*  stats   = (float*)(Ews + (size_t)NB * BS * BS);  // [B][32][4096]
    float*  rowstat = stats + (size_t)NB * 32 * 4096;        // [B][4096]

    dim3 blk(256);
    proj_kernel<<<dim3(4, 128, 3), blk, 0, stream>>>(
        queries, keys, values, Wq, bq, Wk, bk, Wv, bv, qb, kb, vT);

    dim3 gqk(BS / 128, BS / 128, NB);
    qk_kernel<<<gqk, blk, 0, stream>>>(qb, kb, attn, Ews, stats);

    reduce_kernel<<<dim3(512), blk, 0, stream>>>(stats, rowstat, (float4*)ctx);

    pv_kernel<<<dim3(10240), dim3(64), 0, stream>>>(attn, vT, Ews, rowstat, ctx);
}

// Round 14
// 385.046 us; speedup vs baseline: 1.2343x; 1.2343x over previous
//
#include <hip/hip_runtime.h>
#include <hip/hip_bf16.h>
#include <stdint.h>

#define NB 4
#define BS 4096
#define BH 512

typedef __attribute__((ext_vector_type(8))) short bf16x8;
typedef __attribute__((ext_vector_type(4))) float f32x4;

#define VMC(n) asm volatile("s_waitcnt vmcnt(" #n ")" ::: "memory")
#define LGK0()  asm volatile("s_waitcnt lgkmcnt(0)" ::: "memory")

static __device__ __forceinline__ ushort f2bf(float x) {
    union { float f; uint32_t u; } c; c.f = x;
    uint32_t r = c.u + 0x7FFFu + ((c.u >> 16) & 1u);
    return (ushort)(r >> 16);
}
static __device__ __forceinline__ float bf2f(ushort u) {
    union { uint32_t u; float f; } c; c.u = (uint32_t)u << 16;
    return c.f;
}

// async global -> LDS, 16B per lane. dest = wave-uniform base + lane*16.
static __device__ __forceinline__ void gl16(const void* gptr, void* lptr) {
    __builtin_amdgcn_global_load_lds(
        (const __attribute__((address_space(1))) void*)gptr,
        (__attribute__((address_space(3))) void*)lptr, 16, 0, 0);
}

// ---------------------------------------------------------------------------
// Fused projection GEMMs: z = 0/1/2 -> Q/K/V.  Y = X W^T + b, bf16 out.
// ---------------------------------------------------------------------------
__global__ __launch_bounds__(256) void proj_kernel(
    const float* __restrict__ Xq, const float* __restrict__ Xk, const float* __restrict__ Xv,
    const float* __restrict__ Wq, const float* __restrict__ bq,
    const float* __restrict__ Wk, const float* __restrict__ bk,
    const float* __restrict__ Wv, const float* __restrict__ bv,
    ushort* __restrict__ qb, ushort* __restrict__ kb, ushort* __restrict__ vT)
{
    const int z = blockIdx.z;
    const float* X    = (z == 0) ? Xq : (z == 1) ? Xk : Xv;
    const float* W    = (z == 0) ? Wq : (z == 1) ? Wk : Wv;
    const float* bias = (z == 0) ? bq : (z == 1) ? bk : bv;
    ushort* out       = (z == 0) ? qb : (z == 1) ? kb : vT;
    const bool TR = (z == 2);

    __shared__ ushort As[128 * 32];
    __shared__ ushort Bs[128 * 32];
    const int tid  = threadIdx.x;
    const int lane = tid & 63;
    const int wave = tid >> 6;
    const int wr = wave >> 1, wc = wave & 1;
    const int bi = blockIdx.y, bj = blockIdx.x;

    f32x4 acc[4][4];
    #pragma unroll
    for (int m = 0; m < 4; m++)
        #pragma unroll
        for (int n = 0; n < 4; n++) acc[m][n] = (f32x4)0.0f;

    const int r  = tid >> 1;
    const int kg = (tid & 1) * 16;
    const int kq = (lane >> 4) * 8;
    const int fr = lane & 15;

    for (int kt = 0; kt < 512; kt += 32) {
        {
            const float* src = X + (size_t)(bi * 128 + r) * 512 + kt + kg;
            ushort tmp[16];
            #pragma unroll
            for (int j = 0; j < 4; j++) {
                float4 v = *reinterpret_cast<const float4*>(src + j * 4);
                tmp[j*4+0] = f2bf(v.x); tmp[j*4+1] = f2bf(v.y);
                tmp[j*4+2] = f2bf(v.z); tmp[j*4+3] = f2bf(v.w);
            }
            ushort* dst = &As[r * 32 + kg];
            *reinterpret_cast<uint4*>(dst)     = *reinterpret_cast<const uint4*>(tmp);
            *reinterpret_cast<uint4*>(dst + 8) = *reinterpret_cast<const uint4*>(tmp + 8);
        }
        {
            const float* src = W + (size_t)(bj * 128 + r) * 512 + kt + kg;
            ushort tmp[16];
            #pragma unroll
            for (int j = 0; j < 4; j++) {
                float4 v = *reinterpret_cast<const float4*>(src + j * 4);
                tmp[j*4+0] = f2bf(v.x); tmp[j*4+1] = f2bf(v.y);
                tmp[j*4+2] = f2bf(v.z); tmp[j*4+3] = f2bf(v.w);
            }
            ushort* dst = &Bs[r * 32 + kg];
            *reinterpret_cast<uint4*>(dst)     = *reinterpret_cast<const uint4*>(tmp);
            *reinterpret_cast<uint4*>(dst + 8) = *reinterpret_cast<const uint4*>(tmp + 8);
        }
        __syncthreads();

        bf16x8 af[4], bf[4];
        #pragma unroll
        for (int m = 0; m < 4; m++)
            af[m] = *reinterpret_cast<const bf16x8*>(&As[(wr*64 + m*16 + fr) * 32 + kq]);
        #pragma unroll
        for (int n = 0; n < 4; n++)
            bf[n] = *reinterpret_cast<const bf16x8*>(&Bs[(wc*64 + n*16 + fr) * 32 + kq]);
        #pragma unroll
        for (int m = 0; m < 4; m++)
            #pragma unroll
            for (int n = 0; n < 4; n++)
                acc[m][n] = __builtin_amdgcn_mfma_f32_16x16x32_bf16(af[m], bf[n], acc[m][n], 0, 0, 0);
        __syncthreads();
    }

    const int fq = lane >> 4;
    #pragma unroll
    for (int n = 0; n < 4; n++) {
        const int col = bj * 128 + wc * 64 + n * 16 + fr;
        const float bv2 = bias[col];
        #pragma unroll
        for (int m = 0; m < 4; m++) {
            const int row0 = bi * 128 + wr * 64 + m * 16 + fq * 4;
            if (TR) {
                const int b = row0 >> 12;
                const int s = row0 & 4095;
                ushort4 pk;
                pk.x = f2bf(acc[m][n][0] + bv2);
                pk.y = f2bf(acc[m][n][1] + bv2);
                pk.z = f2bf(acc[m][n][2] + bv2);
                pk.w = f2bf(acc[m][n][3] + bv2);
                *reinterpret_cast<ushort4*>(&out[((size_t)b * 512 + col) * 4096 + s]) = pk;
            } else {
                #pragma unroll
                for (int j = 0; j < 4; j++)
                    out[(size_t)(row0 + j) * 512 + col] = f2bf(acc[m][n][j] + bv2);
            }
        }
    }
}

// ---------------------------------------------------------------------------
// QK^T 128x128 (R7 exact: __syncthreads dbuf loop, compiler-scheduled).
// e = exp(s*scale), bf16 E + partial row sums. Upper tiles: fp32 zeros.
// Diag masked cells: E=0 (pv writes the fp32 zeros).
// ---------------------------------------------------------------------------
__global__ __launch_bounds__(256) void qk_kernel(const ushort* __restrict__ qb,
                                                 const ushort* __restrict__ kb,
                                                 float* __restrict__ attn,
                                                 ushort* __restrict__ Ews,
                                                 float* __restrict__ stats)
{
    // XCD-aware bijective swizzle: nwg = 4096
    const int flat = blockIdx.x + (blockIdx.y << 5) + (blockIdx.z << 10);
    const int s    = (flat & 7) * 512 + (flat >> 3);
    const int bj = s & 31, bi = (s >> 5) & 31, b = s >> 10;

    float* aout = attn + (size_t)b * BS * BS;
    const int tid = threadIdx.x;

    if (bj > bi) {  // fully masked tile -> fp32 zeros (final output value)
        const int r  = tid >> 1;
        const int cg = (tid & 1) * 64;
        float4 z = make_float4(0.f, 0.f, 0.f, 0.f);
        float* dst = aout + (size_t)(bi * 128 + r) * BS + bj * 128 + cg;
        #pragma unroll
        for (int j = 0; j < 16; j++) reinterpret_cast<float4*>(dst)[j] = z;
        return;
    }

    __shared__ ushort A0[128 * 32], A1[128 * 32];
    __shared__ ushort B0[128 * 32], B1[128 * 32];
    __shared__ float red[128][2];
    const int lane = tid & 63;
    const int wave = tid >> 6;
    const int wr = wave >> 1, wc = wave & 1;

    f32x4 acc[4][4];
    #pragma unroll
    for (int m = 0; m < 4; m++)
        #pragma unroll
        for (int n = 0; n < 4; n++) acc[m][n] = (f32x4)0.0f;

    const ushort* Qb = qb + (size_t)(b * BS + bi * 128) * 512;
    const ushort* Kb = kb + (size_t)(b * BS + bj * 128) * 512;

    const int c0 = wave * 2, c1 = wave * 2 + 1;
    const int glr = lane >> 2;
    const int gsw = ((lane & 3) ^ (glr & 3)) * 8;   // inverse-swizzled granule
    const ushort* ga0 = Qb + (size_t)(c0 * 16 + glr) * 512 + gsw;
    const ushort* ga1 = Qb + (size_t)(c1 * 16 + glr) * 512 + gsw;
    const ushort* gb0 = Kb + (size_t)(c0 * 16 + glr) * 512 + gsw;
    const ushort* gb1 = Kb + (size_t)(c1 * 16 + glr) * 512 + gsw;
    ushort* a0l0 = &A0[c0 * 512]; ushort* a0l1 = &A0[c1 * 512];
    ushort* a1l0 = &A1[c0 * 512]; ushort* a1l1 = &A1[c1 * 512];
    ushort* b0l0 = &B0[c0 * 512]; ushort* b0l1 = &B0[c1 * 512];
    ushort* b1l0 = &B1[c0 * 512]; ushort* b1l1 = &B1[c1 * 512];

    const int fr = lane & 15;
    const int fq = lane >> 4;
    const int kqs = (fq ^ (fr & 3)) * 8;   // swizzled read slot

    auto domfma = [&](const ushort* Ab, const ushort* Bb) {
        bf16x8 af[4], bf[4];
        #pragma unroll
        for (int m = 0; m < 4; m++)
            af[m] = *reinterpret_cast<const bf16x8*>(&Ab[(wr*64 + m*16 + fr) * 32 + kqs]);
        #pragma unroll
        for (int n = 0; n < 4; n++)
            bf[n] = *reinterpret_cast<const bf16x8*>(&Bb[(wc*64 + n*16 + fr) * 32 + kqs]);
        __builtin_amdgcn_s_setprio(1);
        #pragma unroll
        for (int m = 0; m < 4; m++)
            #pragma unroll
            for (int n = 0; n < 4; n++)
                acc[m][n] = __builtin_amdgcn_mfma_f32_16x16x32_bf16(af[m], bf[n], acc[m][n], 0, 0, 0);
        __builtin_amdgcn_s_setprio(0);
    };

    // prologue: stage tile 0 into buffers 0
    gl16(ga0, a0l0); gl16(ga1, a0l1);
    gl16(gb0, b0l0); gl16(gb1, b0l1);
    __syncthreads();

    for (int kt = 0; kt < 512; kt += 64) {
        gl16(ga0 + kt + 32, a1l0); gl16(ga1 + kt + 32, a1l1);
        gl16(gb0 + kt + 32, b1l0); gl16(gb1 + kt + 32, b1l1);
        domfma(A0, B0);
        __syncthreads();
        if (kt + 64 < 512) {
            gl16(ga0 + kt + 64, a0l0); gl16(ga1 + kt + 64, a0l1);
            gl16(gb0 + kt + 64, b0l0); gl16(gb1 + kt + 64, b0l1);
        }
        domfma(A1, B1);
        __syncthreads();
    }

    const float scaling = 0.044194173824159216f;  // 1/sqrt(512)
    ushort* Eb = Ews + ((size_t)b << 24);
    const bool diag = (bi == bj);

    #pragma unroll
    for (int m = 0; m < 4; m++) {
        #pragma unroll
        for (int j = 0; j < 4; j++) {
            const int r_loc = wr * 64 + m * 16 + fq * 4 + j;
            const int grow  = bi * 128 + r_loc;
            float sum = 0.0f;
            #pragma unroll
            for (int n = 0; n < 4; n++) {
                const int col = bj * 128 + wc * 64 + n * 16 + fr;
                const bool masked = diag && (col > grow);
                float e = masked ? 0.0f : __expf(acc[m][n][j] * scaling);
                Eb[(size_t)grow * BS + col] = f2bf(e);
                sum += e;
            }
            #pragma unroll
            for (int o = 1; o < 16; o <<= 1) sum += __shfl_xor(sum, o);
            if (fr == 0) red[r_loc][wc] = sum;
        }
    }
    __syncthreads();
    if (tid < 128)
        stats[(size_t)(b * 32 + bj) * 4096 + bi * 128 + tid] = red[tid][0] + red[tid][1];
}

// ---------------------------------------------------------------------------
// Merge per-tile sums into per-row 1/sum AND zero ctx. Grid: 512 x 256.
// ---------------------------------------------------------------------------
__global__ __launch_bounds__(256) void reduce_kernel(const float* __restrict__ stats,
                                                     float* __restrict__ rowstat,
                                                     float4* __restrict__ ctx4)
{
    const int g = blockIdx.x * 256 + threadIdx.x;   // 0..131071
    const float4 z = make_float4(0.f, 0.f, 0.f, 0.f);
    #pragma unroll
    for (int i = 0; i < 16; i++)
        ctx4[(size_t)i * 131072 + g] = z;

    if (g < 16384) {
        const int b = g >> 12, i = g & 4095;
        const int nt = (i >> 7) + 1;
        float S = 0.0f;
        for (int t = 0; t < nt; t++)
            S += stats[(size_t)(b * 32 + t) * 4096 + i];
        rowstat[g] = 1.0f / S;
    }
}

// ---------------------------------------------------------------------------
// PV + attn-write (R11 exact, best-measured pv = 177 us). Counted-vmcnt
// pipelined, 4-wave blocks, 1280 blocks, dbuf V+E in LDS, in-loop attn
// stores from waves 0/1, ctx via fp32 atomics.
// ---------------------------------------------------------------------------
__global__ __launch_bounds__(256) void pv_kernel(float* __restrict__ attn,
                                                 const ushort* __restrict__ vT,
                                                 const ushort* __restrict__ Ews,
                                                 const float* __restrict__ rowstat,
                                                 float* __restrict__ ctx)
{
    const int b = blockIdx.x & 3;                 // batch -> XCD affinity
    const int f = blockIdx.x >> 2;                // 0..319
    int w = 3;
    if (f < 32)       w = 0;
    else if (f < 96)  w = 1;
    else if (f < 192) w = 2;
    const int start = 16 * w * (w + 1);
    const int local = f - start;
    const int bi32  = (w << 5) + local / (w + 1);
    const int ks    = local % (w + 1);

    const int nt_cov = ((bi32 >> 2) + 1) << 2;    // cover to 128-tile boundary
    const int t0 = ks * 32;
    const int t1 = min(nt_cov, t0 + 32);

    __shared__ ushort V0[512 * 32], V1[512 * 32];   // 32 KB each
    __shared__ ushort E0l[32 * 32], E1l[32 * 32];   // 2 KB each

    const int tid  = threadIdx.x;
    const int lane = tid & 63;
    const int wave = tid >> 6;
    const int fr = lane & 15;
    const int fq = lane >> 4;
    const int kqs = (fq ^ (fr & 3)) * 8;

    f32x4 acc[2][8];
    #pragma unroll
    for (int m = 0; m < 2; m++)
        #pragma unroll
        for (int n = 0; n < 8; n++) acc[m][n] = (f32x4)0.0f;

    const int grow0 = bi32 * 32;
    const float rinv0 = rowstat[b * 4096 + grow0 + fr];
    const float rinv1 = rowstat[b * 4096 + grow0 + 16 + fr];

    const int glr = lane >> 2;
    const int gsw = ((lane & 3) ^ (glr & 3)) * 8;

    const ushort* Vb = vT + (size_t)b * 512 * BS;
    const ushort* gV[8];
    #pragma unroll
    for (int q = 0; q < 8; q++)
        gV[q] = Vb + (size_t)((wave * 8 + q) * 16 + glr) * BS + gsw;

    const ushort* Ebase = Ews + ((size_t)b << 24);
    const ushort* gE0 = Ebase + (size_t)(grow0 + glr) * BS + gsw;        // rows 0..15
    const ushort* gE1 = Ebase + (size_t)(grow0 + 16 + glr) * BS + gsw;   // rows 16..31

    float* AttnB = attn + (size_t)b * BS * BS;
    // wave 0 stores rows grow0+fr (p0); wave 1 stores rows grow0+16+fr (p1)
    float* astore = AttnB + (size_t)(grow0 + (wave << 4) + fr) * BS + fq * 8;

    auto stage = [&](int t, int buf) {
        const int k0 = t * 32;
        ushort* Vl = buf ? V1 : V0;
        ushort* El = buf ? E1l : E0l;
        #pragma unroll
        for (int q = 0; q < 8; q++) gl16(gV[q] + k0, &Vl[(wave * 8 + q) * 512]);
        gl16(gE0 + k0, El);          // all 4 waves redundantly (same data)
        gl16(gE1 + k0, El + 512);
    };

    stage(t0, 0);
    int cur = 0;
    for (int t = t0; t < t1; ++t) {
        const bool has = (t + 1 < t1);
        if (has) stage(t + 1, cur ^ 1);
        // per-wave-exact counted wait (in-order retirement makes these sound)
        if (t == t0)        { if (has) VMC(10); else VMC(0); }
        else if (wave < 2)  { if (has) VMC(12); else VMC(2); }
        else                { if (has) VMC(10); else VMC(0); }
        __builtin_amdgcn_sched_barrier(0);
        __builtin_amdgcn_s_barrier();

        const ushort* Vl = cur ? V1 : V0;
        const ushort* El = cur ? E1l : E0l;

        bf16x8 e0 = *reinterpret_cast<const bf16x8*>(&El[fr * 32 + kqs]);
        bf16x8 e1 = *reinterpret_cast<const bf16x8*>(&El[(16 + fr) * 32 + kqs]);

        float p0[8], p1[8];
        #pragma unroll
        for (int j = 0; j < 8; j++) {
            p0[j] = bf2f((ushort)e0[j]) * rinv0;
            p1[j] = bf2f((ushort)e1[j]) * rinv1;
        }

        if (wave < 2) {   // normalized attn store: 2 float4, full-line segments
            const float* ps = wave ? p1 : p0;
            float* dst = astore + (size_t)t * 32;
            *reinterpret_cast<float4*>(dst)     = make_float4(ps[0], ps[1], ps[2], ps[3]);
            *reinterpret_cast<float4*>(dst + 4) = make_float4(ps[4], ps[5], ps[6], ps[7]);
        }

        bf16x8 a0, a1;
        #pragma unroll
        for (int j = 0; j < 8; j++) {
            a0[j] = (short)f2bf(p0[j]);
            a1[j] = (short)f2bf(p1[j]);
        }
        bf16x8 bv[8];
        #pragma unroll
        for (int n = 0; n < 8; n++)
            bv[n] = *reinterpret_cast<const bf16x8*>(&Vl[(wave * 128 + n * 16 + fr) * 32 + kqs]);

        __builtin_amdgcn_s_setprio(1);
        #pragma unroll
        for (int n = 0; n < 8; n++) {
            acc[0][n] = __builtin_amdgcn_mfma_f32_16x16x32_bf16(a0, bv[n], acc[0][n], 0, 0, 0);
            acc[1][n] = __builtin_amdgcn_mfma_f32_16x16x32_bf16(a1, bv[n], acc[1][n], 0, 0, 0);
        }
        __builtin_amdgcn_s_setprio(0);

        LGK0();
        __builtin_amdgcn_s_barrier();
        cur ^= 1;
    }

    float* Crow = ctx + (size_t)b * BS * 512;
    const bool single = (w == 0);
    #pragma unroll
    for (int n = 0; n < 8; n++) {
        const int col = wave * 128 + n * 16 + fr;
        #pragma unroll
        for (int m = 0; m < 2; m++) {
            const int row0 = grow0 + m * 16 + fq * 4;
            #pragma unroll
            for (int j = 0; j < 4; j++) {
                float* dst = &Crow[(size_t)(row0 + j) * 512 + col];
                if (single) *dst = acc[m][n][j];
                else        unsafeAtomicAdd(dst, acc[m][n][j]);
            }
        }
    }
}

extern "C" void kernel_launch(void* const* d_in, const int* in_sizes, int n_in,
                              void* d_out, int out_size, void* d_ws, size_t ws_size,
                              hipStream_t stream)
{
    const float* queries = (const float*)d_in[0];
    const float* keys    = (const float*)d_in[1];
    const float* values  = (const float*)d_in[2];
    const float* Wq = (const float*)d_in[3];
    const float* bq = (const float*)d_in[4];
    const float* Wk = (const float*)d_in[5];
    const float* bk = (const float*)d_in[6];
    const float* Wv = (const float*)d_in[7];
    const float* bv = (const float*)d_in[8];

    float* ctx  = (float*)d_out;                         // [B,S,H]
    float* attn = (float*)d_out + (size_t)NB * BS * BH;  // [B,S,S]

    ushort* qb = (ushort*)d_ws;                          // bf16 [B*S, H]
    ushort* kb = qb + (size_t)NB * BS * BH;
    ushort* vT = kb + (size_t)NB * BS * BH;              // bf16 [B][H][S]
    ushort* Ews = vT + (size_t)NB * BH * BS;             // bf16 [B][S][S]
    float*  stats   = (float*)(Ews + (size_t)NB * BS * BS);  // [B][32][4096]
    float*  rowstat = stats + (size_t)NB * 32 * 4096;        // [B][4096]

    dim3 blk(256);
    proj_kernel<<<dim3(4, 128, 3), blk, 0, stream>>>(
        queries, keys, values, Wq, bq, Wk, bk, Wv, bv, qb, kb, vT);

    dim3 gqk(BS / 128, BS / 128, NB);
    qk_kernel<<<gqk, blk, 0, stream>>>(qb, kb, attn, Ews, stats);

    reduce_kernel<<<dim3(512), blk, 0, stream>>>(stats, rowstat, (float4*)ctx);

    pv_kernel<<<dim3(1280), blk, 0, stream>>>(attn, vT, Ews, rowstat, ctx);
}